// Round 17
// baseline (344.689 us; speedup 1.0000x reference)
//
#include <hip/hip_runtime.h>
#include <math.h>

#pragma clang fp contract(off)

// Problem constants (match reference)
#define PNUM 136500      // sum of f*f
#define HPNUM 68250      // PNUM/2 (exact)
#define BNUM 16
#define TOPK 5000
#define CAP 8192         // candidate capacity per image
#define NB2 1024         // histogram window buckets (covers ord16 of (0.01, 1.0))
#define B2BASE 0xBC00u   // window base: f2ord(0.01)>>16 = 0xBC23 >= 0xBC00
#define NWORDS 79        // ceil(5000/64)
#define GSTRIDE 32       // ecnt padding: 32 u32 = 128 B per image
#define CAPE 65536       // edge capacity per image (expected E ~ 1-3k)
#define NXB 128          // spatial x1 buckets
#define BSTRIDE 5120     // per-image bucket-array stride (>= TOPK)
#define EBUF 3072        // per-block LDS edge buffer

// Workspace layout (bytes).
#define OFF_SC    ((size_t)0)
#define OFF_X1    (OFF_SC + 320000)
#define OFF_Y1    (OFF_X1 + 320000)
#define OFF_X2    (OFF_Y1 + 320000)
#define OFF_Y2    (OFF_X2 + 320000)
#define OFF_AREA  (OFF_Y2 + 320000)       // ends 1,920,000
#define OFF_HIST  ((size_t)1920000)       // 16*1024*4 = 65,536
#define OFF_CUT   (OFF_HIST + 65536)      // 64
#define OFF_SBASE (OFF_CUT + 64)          // 16*1024*4 = 65,536
#define OFF_GBCUR (OFF_SBASE + 65536)     // 16*1024*64 = 1,048,576 (padded ctrs)
#define OFF_KEYS  (OFF_GBCUR + 1048576)   // 16*8192*8 = 1,048,576
#define OFF_ECNT  (OFF_KEYS + 1048576)    // 2048
#define OFF_EDGE  (OFF_ECNT + 2048)       // 16*65536*4 = 4,194,304
#define OFF_GRP   (OFF_EDGE + 4194304)    // 4,194,304
// bucket arrays overlaid on GRP (dead before k_nms2 writes grouped):
#define OFF_BOFS  (OFF_GRP)               // 16*130*4 (pad to 16384)
#define OFF_SIDX  (OFF_GRP + 16384)       // u32 [16*5120]
#define OFF_SBX1  (OFF_SIDX + 327680)
#define OFF_SBX2  (OFF_SBX1 + 327680)
#define OFF_SBY1  (OFF_SBX2 + 327680)
#define OFF_SBY2  (OFF_SBY1 + 327680)
#define OFF_SBAR  (OFF_SBY2 + 327680)

__device__ __forceinline__ unsigned f2ord(float f) {
    unsigned u = __float_as_uint(f);
    return (u & 0x80000000u) ? ~u : (u | 0x80000000u);
}
__device__ __forceinline__ float ord2f(unsigned o) {
    unsigned u = (o & 0x80000000u) ? (o ^ 0x80000000u) : ~o;
    return __uint_as_float(u);
}
// monotone x1 -> bucket map; identical in k_bucket and k_pair3
__device__ __forceinline__ int bucketOf(float x) {
    int b = (int)((x + 0.6f) * 71.111115f);   // 128 buckets over [-0.6, 1.2]
    return (b < 0) ? 0 : ((b > 127) ? 127 : b);
}

// K1: per-image histogram over the 1024-bucket window in LDS + atomic merge.
__global__ void __launch_bounds__(256) k_hist(const float* __restrict__ conf,
                                              unsigned* __restrict__ hist) {
    __shared__ unsigned lh[NB2];
    int img = blockIdx.y;
    for (int i = threadIdx.x; i < NB2; i += 256) lh[i] = 0;
    __syncthreads();
    const float4* src = (const float4*)(conf + (size_t)img * PNUM * 2);
    int stride = gridDim.x * 256;
    for (int q = blockIdx.x * 256 + threadIdx.x; q < HPNUM; q += stride) {
        float4 v = src[q];
        if (v.y > 0.01f) atomicAdd(&lh[(f2ord(v.y) >> 16) - B2BASE], 1u);
        if (v.w > 0.01f) atomicAdd(&lh[(f2ord(v.w) >> 16) - B2BASE], 1u);
    }
    __syncthreads();
    unsigned* h = hist + (size_t)img * NB2;
    for (int i = threadIdx.x; i < NB2; i += 256) {
        unsigned c = lh[i];
        if (c) atomicAdd(&h[i], c);
    }
}

// K2: cutoff + per-bucket suffix base ranks (segment start slots).
__global__ void __launch_bounds__(256) k_cutoff2(const unsigned* __restrict__ hist,
                                                 unsigned* __restrict__ cut,
                                                 unsigned* __restrict__ sbase) {
    __shared__ unsigned csum[256], suf[256];
    int img = blockIdx.x;
    int t = threadIdx.x;
    const unsigned* h = hist + (size_t)img * NB2;
    unsigned h0 = h[t * 4], h1 = h[t * 4 + 1], h2 = h[t * 4 + 2], h3 = h[t * 4 + 3];
    csum[t] = h0 + h1 + h2 + h3;
    __syncthreads();
    if (t == 0) {
        unsigned a = 0;
        for (int g = 255; g >= 0; --g) { unsigned c = csum[g]; suf[g] = a; a += c; }
        // cutoff: highest bucket such that count(>= it) >= TOPK
        unsigned acc = 0, before = 0;
        int c = -1;
        for (int cc = 255; cc >= 0; --cc) {
            if (acc + csum[cc] >= (unsigned)TOPK) { c = cc; before = acc; break; }
            acc += csum[cc];
        }
        unsigned cutb = B2BASE;
        if (c >= 0) {
            unsigned s2 = before;
            cutb = B2BASE + (unsigned)c * 4u;
            for (int b = c * 4 + 3; b >= c * 4; --b) {
                s2 += h[b];
                if (s2 >= (unsigned)TOPK) { cutb = B2BASE + (unsigned)b; break; }
            }
        }
        cut[img] = cutb;
    }
    __syncthreads();
    unsigned a = suf[t];
    unsigned* sb = sbase + (size_t)img * NB2 + t * 4;
    sb[3] = a;
    sb[2] = a + h3;
    sb[1] = a + h3 + h2;
    sb[0] = a + h3 + h2 + h1;
}

// K3: gather candidates directly into their bucket segment (rank-scatter).
// Within-segment order is arbitrary (k_ssort fixes it).
__global__ void __launch_bounds__(256) k_gather2(
        const float* __restrict__ conf, const unsigned* __restrict__ cut,
        const unsigned* __restrict__ sbase, unsigned* __restrict__ gbcur,
        unsigned long long* __restrict__ keys) {
    int q = blockIdx.x * 256 + threadIdx.x;
    int img = blockIdx.y;
    if (q >= HPNUM) return;
    unsigned cutb = cut[img];
    float4 v = ((const float4*)(conf + (size_t)img * PNUM * 2))[q];
    const unsigned* sb = sbase + (size_t)img * NB2;
    unsigned* gc = gbcur + (size_t)img * NB2 * 16;
    unsigned long long* kp = keys + (size_t)img * CAP;
    #pragma unroll
    for (int e = 0; e < 2; ++e) {
        float s = e ? v.w : v.y;
        if (s > 0.01f) {
            unsigned o = f2ord(s);
            if ((o >> 16) >= cutb) {
                unsigned wb = (o >> 16) - B2BASE;
                unsigned pos = sb[wb] + atomicAdd(&gc[wb * 16], 1u);
                if (pos < (unsigned)CAP)
                    kp[pos] = ((unsigned long long)o << 32)
                              | (unsigned)(~(unsigned)(2 * q + e));
            }
        }
    }
}

// K4: per-segment descending sort (<=1024 keys). One block per (bucket,img);
// empty / below-cutoff / singleton segments exit immediately.
__global__ void __launch_bounds__(256) k_ssort(
        unsigned long long* __restrict__ keys, const unsigned* __restrict__ hist,
        const unsigned* __restrict__ cut, const unsigned* __restrict__ sbase) {
    int img = blockIdx.y;
    int b = blockIdx.x;
    if (B2BASE + (unsigned)b < cut[img]) return;
    unsigned cnt = hist[(size_t)img * NB2 + b];
    if (cnt <= 1) return;
    if (cnt > 1024) cnt = 1024;          // capacity guard (stat. unreachable)
    unsigned base = sbase[(size_t)img * NB2 + b];
    __shared__ unsigned long long sk[1024];
    unsigned long long* kp = keys + (size_t)img * CAP + base;
    int tid = threadIdx.x;
    for (int i = tid; i < 1024; i += 256) sk[i] = (i < (int)cnt) ? kp[i] : 0ull;
    __syncthreads();
    for (int k = 2; k <= 1024; k <<= 1) {
        for (int j = k >> 1; j > 0; j >>= 1) {
            for (int t = tid; t < 512; t += 256) {
                int i = ((t & ~(j - 1)) << 1) | (t & (j - 1));
                int p = i | j;
                bool desc = ((i & k) == 0);
                unsigned long long a = sk[i], bb = sk[p];
                bool sw = desc ? (a < bb) : (a > bb);
                if (sw) { sk[i] = bb; sk[p] = a; }
            }
            __syncthreads();
        }
    }
    for (int i = tid; i < (int)cnt; i += 256) kp[i] = sk[i];
}

// K5: decode sorted top-5000 keys -> SC/X1/Y1/X2/Y2/AREA (fully parallel)
__global__ void __launch_bounds__(256) k_decode(
        const unsigned long long* __restrict__ keys,
        const float* __restrict__ loc, const float* __restrict__ pri,
        float* __restrict__ SC, float* __restrict__ X1, float* __restrict__ Y1,
        float* __restrict__ X2, float* __restrict__ Y2, float* __restrict__ AREA) {
    int gidx = blockIdx.x * 256 + threadIdx.x;
    if (gidx >= BNUM * TOPK) return;
    int img = gidx / TOPK;
    int r = gidx - img * TOPK;
    unsigned long long key = keys[(size_t)img * CAP + r];
    size_t o = (size_t)img * TOPK + r;
    if (key != 0ull) {
        unsigned ordv = (unsigned)(key >> 32);
        float s = ord2f(ordv);
        unsigned p = ~(unsigned)(key & 0xFFFFFFFFull);
        const float* lp = loc + ((size_t)img * PNUM + p) * 4;
        const float* pp = pri + (size_t)p * 4;
        float lx = lp[0], ly = lp[1], lw = lp[2], lh = lp[3];
        float px = pp[0], py = pp[1], pw = pp[2], ph = pp[3];
        float cx = px + (lx * 0.1f) * pw;
        float cy = py + (ly * 0.1f) * ph;
        float w = pw * expf(lw * 0.2f);
        float h = ph * expf(lh * 0.2f);
        float x1 = cx - w * 0.5f;
        float y1 = cy - h * 0.5f;
        float x2 = x1 + w;
        float y2 = y1 + h;
        SC[o] = s; X1[o] = x1; Y1[o] = y1; X2[o] = x2; Y2[o] = y2;
        AREA[o] = (x2 - x1) * (y2 - y1);
    } else {
        SC[o] = -1.0f; X1[o] = 0.f; Y1[o] = 0.f; X2[o] = 0.f; Y2[o] = 0.f;
        AREA[o] = 0.f;
    }
}

// K6: spatial bucketing by x1 (counting sort into 128 buckets), gathered
// box copies so the pair scan reads contiguously. 1 block/image.
__global__ void __launch_bounds__(256) k_bucket(
        const float* __restrict__ X1, const float* __restrict__ X2,
        const float* __restrict__ Y1, const float* __restrict__ Y2,
        const float* __restrict__ AREA,
        unsigned* __restrict__ bofs, unsigned* __restrict__ sidx,
        float* __restrict__ sbx1, float* __restrict__ sbx2,
        float* __restrict__ sby1, float* __restrict__ sby2,
        float* __restrict__ sbar) {
    __shared__ unsigned bcnt[NXB], bpre[NXB + 1], bcur[NXB];
    int img = blockIdx.x;
    int tid = threadIdx.x;
    if (tid < NXB) bcnt[tid] = 0;
    __syncthreads();
    size_t ib = (size_t)img * TOPK;
    for (int r = tid; r < TOPK; r += 256)
        atomicAdd(&bcnt[bucketOf(X1[ib + r])], 1u);
    __syncthreads();
    if (tid == 0) {
        unsigned a = 0;
        for (int b = 0; b < NXB; ++b) { bpre[b] = a; a += bcnt[b]; }
        bpre[NXB] = a;
    }
    __syncthreads();
    if (tid < NXB) bcur[tid] = bpre[tid];
    if (tid <= NXB) bofs[img * 130 + tid] = bpre[tid];
    __syncthreads();
    int base = img * BSTRIDE;
    for (int r = tid; r < TOPK; r += 256) {
        float x = X1[ib + r];
        unsigned s = atomicAdd(&bcur[bucketOf(x)], 1u);
        sidx[base + s] = (unsigned)r;
        sbx1[base + s] = x;
        sbx2[base + s] = X2[ib + r];
        sby1[base + s] = Y1[ib + r];
        sby2[base + s] = Y2[ib + r];
        sbar[base + s] = AREA[ib + r];
    }
}

// K7: wave-per-SORTED-SLOT bucketed pair search. Wave w handles slot s:
// preamble reads sb*[s] (consecutive s across waves -> L1 line reuse, no
// scattered over-fetch). 64 lanes stride the candidate range; pair emitted
// by the box with smaller x1 (tie: smaller original index). IoU math
// bit-identical to reference. Ballot-compacted LDS emission.
__global__ void __launch_bounds__(256) k_pair3(
        const unsigned* __restrict__ bofs, const unsigned* __restrict__ sidx,
        const float* __restrict__ sbx1, const float* __restrict__ sbx2,
        const float* __restrict__ sby1, const float* __restrict__ sby2,
        const float* __restrict__ sbar,
        unsigned* __restrict__ ecnt, unsigned* __restrict__ edges) {
    __shared__ unsigned ebuf[EBUF];
    __shared__ unsigned ecl, ebase;
    int img = blockIdx.y;
    int wid = threadIdx.x >> 6;
    int lane = threadIdx.x & 63;
    int s = blockIdx.x * 4 + wid;                 // one wave per sorted slot
    if (threadIdx.x == 0) ecl = 0;
    __syncthreads();
    unsigned* ec = ecnt + (size_t)img * GSTRIDE;
    unsigned* eg = edges + (size_t)img * CAPE;
    if (s < TOPK) {
        int base = img * BSTRIDE;
        float x1 = sbx1[base + s], x2 = sbx2[base + s];
        float y1 = sby1[base + s], y2 = sby2[base + s];
        float ar = sbar[base + s];
        unsigned r = sidx[base + s];
        int b1 = bucketOf(x1), b2 = bucketOf(x2);
        const unsigned* bo = bofs + img * 130;
        unsigned s0 = bo[b1], s1 = bo[b2 + 1];
        for (unsigned sb = s0 + lane; ; sb += 64) {
            bool hit = false;
            unsigned edge = 0;
            if (sb < s1) {
                float bx1 = sbx1[base + sb];
                if (bx1 >= x1) {
                    unsigned r2 = sidx[base + sb];
                    if (!(bx1 == x1 && r2 <= r)) {
                        float bx2 = sbx2[base + sb];
                        float dx = fminf(x2, bx2) - fmaxf(x1, bx1);
                        if (dx > 0.0f) {
                            float by1 = sby1[base + sb];
                            float by2 = sby2[base + sb];
                            float dy = fminf(y2, by2) - fmaxf(y1, by1);
                            if (dy > 0.0f) {
                                float inter = dx * dy;
                                float iou = inter /
                                    (sbar[base + sb] + ar - inter);
                                if (iou > 0.3f) {
                                    unsigned su = (r < r2) ? r : r2;
                                    unsigned vi = (r < r2) ? r2 : r;
                                    edge = (vi << 13) | su;
                                    hit = true;
                                }
                            }
                        }
                    }
                }
            }
            unsigned long long bal = __ballot(hit);
            if (bal) {
                int n = __popcll(bal);
                unsigned wb = 0;
                if (lane == 0) wb = atomicAdd(&ecl, (unsigned)n);
                wb = __shfl(wb, 0, 64);
                if (hit) {
                    unsigned long long lt =
                        (lane == 0) ? 0ull : ((1ull << lane) - 1ull);
                    unsigned p = wb + (unsigned)__popcll(bal & lt);
                    if (p < (unsigned)EBUF) ebuf[p] = edge;
                    else {
                        unsigned gp = atomicAdd(ec, 1u);
                        if (gp < (unsigned)CAPE) eg[gp] = edge;
                    }
                }
            }
            if (sb - lane + 64 >= s1) break;      // uniform across wave
        }
    }
    __syncthreads();
    unsigned n = min(ecl, (unsigned)EBUF);
    if (threadIdx.x == 0 && n) ebase = atomicAdd(ec, n);
    __syncthreads();
    for (unsigned i = threadIdx.x; i < n; i += 256) {
        unsigned p = ebase + i;
        if (p < (unsigned)CAPE) eg[p] = ebuf[i];
    }
}

// K8: sparse greedy resolve + compaction. One block (256) per image.
__global__ void __launch_bounds__(256) k_nms2(
        const float* __restrict__ SC, const float* __restrict__ X1,
        const float* __restrict__ Y1, const float* __restrict__ X2,
        const float* __restrict__ Y2,
        const unsigned* __restrict__ ecnt, const unsigned* __restrict__ edges,
        unsigned* __restrict__ grouped, float* __restrict__ out) {
    __shared__ unsigned cnt[80], ofs[80], cur[80];
    __shared__ unsigned long long keepw[80];
    __shared__ unsigned pfx[80];
    __shared__ unsigned inLo[64], inHi[64];
    __shared__ unsigned remS[2];
    int img = blockIdx.x;
    int tid = threadIdx.x;
    int l = tid & 63;
    int wid = tid >> 6;
    size_t ib = (size_t)img * TOPK;
    const float* sc = SC + ib;

    if (tid < 80) cnt[tid] = 0;
    __syncthreads();
    unsigned E = min(ecnt[(size_t)img * GSTRIDE], (unsigned)CAPE);
    const unsigned* eimg = edges + (size_t)img * CAPE;
    unsigned* gimg = grouped + (size_t)img * CAPE;
    for (unsigned e = tid; e < E; e += 256) atomicAdd(&cnt[eimg[e] >> 19], 1u);
    __syncthreads();
    if (tid == 0) {
        unsigned a = 0;
        for (int w = 0; w < NWORDS; ++w) { ofs[w] = a; a += cnt[w]; }
    }
    __syncthreads();
    if (tid < 80) cur[tid] = ofs[tid];
    __syncthreads();
    for (unsigned e = tid; e < E; e += 256) {
        unsigned ed = eimg[e];
        unsigned p = atomicAdd(&cur[ed >> 19], 1u);
        gimg[p] = ed;
    }
    __syncthreads();

    if (wid == 0) {
        for (int t = 0; t < NWORDS; ++t) {
            inLo[l] = 0; inHi[l] = 0;
            if (l < 2) remS[l] = 0;
            int row = t * 64 + l;
            bool valid = (row < TOPK) && (sc[row] > 0.01f);
            unsigned c = cnt[t], o = ofs[t];
            for (unsigned k = l; k < c; k += 64) {
                unsigned ed = gimg[o + k];
                unsigned v = ed >> 13, s = ed & 8191u;
                unsigned vb = v & 63u, sb = s & 63u;
                int st = (int)(s >> 6);
                if (st == t) {
                    if (sb < 32) atomicOr(&inLo[vb], 1u << sb);
                    else         atomicOr(&inHi[vb], 1u << (sb - 32));
                } else {
                    unsigned long long kw = keepw[st];   // finalized (st < t)
                    if ((kw >> sb) & 1ull) {
                        if (vb < 32) atomicOr(&remS[0], 1u << vb);
                        else         atomicOr(&remS[1], 1u << (vb - 32));
                    }
                }
            }
            __builtin_amdgcn_s_waitcnt(0);   // drain LDS atomics before reads
            unsigned long long inW =
                ((unsigned long long)inHi[l] << 32) | inLo[l];
            unsigned long long remW =
                ((unsigned long long)remS[1] << 32) | remS[0];
            bool alive = valid && !((remW >> l) & 1ull);
            while (true) {                   // exact ascending greedy
                unsigned long long aliveW = __ballot(alive);
                unsigned long long pend =
                    __ballot(alive && ((inW & aliveW) != 0ull));
                if (!pend) break;
                int v = __builtin_ctzll(pend);
                if (l == v) alive = false;
            }
            unsigned long long kwv = __ballot(alive);
            if (l == 0) keepw[t] = kwv;
        }
    }
    __syncthreads();

    if (tid == 0) {
        unsigned acc = 0;
        for (int w = 0; w < NWORDS; ++w) { pfx[w] = acc; acc += (unsigned)__popcll(keepw[w]); }
    }
    __syncthreads();
    const float* x1 = X1 + ib; const float* y1 = Y1 + ib;
    const float* x2 = X2 + ib; const float* y2 = Y2 + ib;
    float* op = out + (((size_t)img * 2) + 1) * TOPK * 5;
    for (int w = wid; w < NWORDS; w += 4) {
        unsigned long long kw = keepw[w];
        if (!kw) continue;
        int row = w * 64 + l;
        if ((kw >> l) & 1ull) {
            int rank = (int)pfx[w] + (int)__popcll(kw & ((1ull << l) - 1ull));
            float* r = op + (size_t)rank * 5;
            r[0] = sc[row]; r[1] = x1[row]; r[2] = y1[row];
            r[3] = x2[row]; r[4] = y2[row];
        }
    }
}

extern "C" void kernel_launch(void* const* d_in, const int* in_sizes, int n_in,
                              void* d_out, int out_size, void* d_ws, size_t ws_size,
                              hipStream_t stream) {
    (void)in_sizes; (void)n_in; (void)ws_size;
    const float* loc  = (const float*)d_in[0];   // (16, 136500, 4)
    const float* conf = (const float*)d_in[1];   // (16*136500, 2)
    const float* pri  = (const float*)d_in[2];   // (136500, 4)
    float* out = (float*)d_out;                  // (16, 2, 5000, 5)
    char* ws = (char*)d_ws;

    float* SC   = (float*)(ws + OFF_SC);
    float* X1   = (float*)(ws + OFF_X1);
    float* Y1   = (float*)(ws + OFF_Y1);
    float* X2   = (float*)(ws + OFF_X2);
    float* Y2   = (float*)(ws + OFF_Y2);
    float* AREA = (float*)(ws + OFF_AREA);
    unsigned* hist = (unsigned*)(ws + OFF_HIST);
    unsigned* cut  = (unsigned*)(ws + OFF_CUT);
    unsigned* sbase = (unsigned*)(ws + OFF_SBASE);
    unsigned* gbcur = (unsigned*)(ws + OFF_GBCUR);
    unsigned long long* keys = (unsigned long long*)(ws + OFF_KEYS);
    unsigned* ecnt = (unsigned*)(ws + OFF_ECNT);
    unsigned* edges = (unsigned*)(ws + OFF_EDGE);
    unsigned* grouped = (unsigned*)(ws + OFF_GRP);
    unsigned* bofs = (unsigned*)(ws + OFF_BOFS);
    unsigned* sidx = (unsigned*)(ws + OFF_SIDX);
    float* sbx1 = (float*)(ws + OFF_SBX1);
    float* sbx2 = (float*)(ws + OFF_SBX2);
    float* sby1 = (float*)(ws + OFF_SBY1);
    float* sby2 = (float*)(ws + OFF_SBY2);
    float* sbar = (float*)(ws + OFF_SBAR);

    hipMemsetAsync(d_out, 0, (size_t)out_size * sizeof(float), stream);
    // zero hist..ecnt contiguously (covers cut/sbase/gbcur/keys/ecnt)
    hipMemsetAsync(ws + OFF_HIST, 0, (OFF_ECNT + 2048) - OFF_HIST, stream);

    dim3 gh1(16, BNUM);                          // 16 grid-stride blocks/image
    k_hist<<<gh1, 256, 0, stream>>>(conf, hist);
    k_cutoff2<<<BNUM, 256, 0, stream>>>(hist, cut, sbase);
    dim3 gh2((HPNUM + 255) / 256, BNUM);
    k_gather2<<<gh2, 256, 0, stream>>>(conf, cut, sbase, gbcur, keys);
    dim3 gs(NB2, BNUM);                          // per-segment sorts
    k_ssort<<<gs, 256, 0, stream>>>(keys, hist, cut, sbase);
    k_decode<<<(BNUM * TOPK + 255) / 256, 256, 0, stream>>>(
        keys, loc, pri, SC, X1, Y1, X2, Y2, AREA);

    // sparse NMS: spatial bucketing + slot-mapped pair search + resolve
    k_bucket<<<BNUM, 256, 0, stream>>>(X1, X2, Y1, Y2, AREA,
                                       bofs, sidx, sbx1, sbx2, sby1, sby2, sbar);
    dim3 pg((TOPK + 3) / 4, BNUM);               // one wave per sorted slot
    k_pair3<<<pg, 256, 0, stream>>>(bofs, sidx, sbx1, sbx2, sby1, sby2, sbar,
                                    ecnt, edges);
    k_nms2<<<BNUM, 256, 0, stream>>>(SC, X1, Y1, X2, Y2, ecnt, edges, grouped, out);
}

// Round 18
// 325.378 us; speedup vs baseline: 1.0593x; 1.0593x over previous
//
#include <hip/hip_runtime.h>
#include <math.h>

#pragma clang fp contract(off)

// Problem constants (match reference)
#define PNUM 136500      // sum of f*f
#define HPNUM 68250      // PNUM/2 (exact)
#define BNUM 16
#define TOPK 5000
#define CAP 8192         // candidate capacity per image
#define NB2 1024         // histogram window buckets (covers ord16 of (0.01, 1.0))
#define B2BASE 0xBC00u   // window base: f2ord(0.01)>>16 = 0xBC23 >= 0xBC00
#define NWORDS 79        // ceil(5000/64)
#define GSTRIDE 32       // ecnt padding: 32 u32 = 128 B per image
#define CAPE 65536       // edge capacity per image (expected E ~ 1-3k)
#define ELDS 10240       // LDS grouped-edge capacity (global fallback beyond)
#define NXB 128          // spatial x1 buckets
#define BSTRIDE 5120     // per-image bucket-array stride (>= TOPK)
#define EBUF 3072        // per-block LDS edge buffer

// Workspace layout (bytes).
#define OFF_SC    ((size_t)0)
#define OFF_X1    (OFF_SC + 320000)
#define OFF_Y1    (OFF_X1 + 320000)
#define OFF_X2    (OFF_Y1 + 320000)
#define OFF_Y2    (OFF_X2 + 320000)
#define OFF_AREA  (OFF_Y2 + 320000)       // ends 1,920,000
#define OFF_HIST  ((size_t)1920000)       // 16*1024*4 = 65,536
#define OFF_CUT   (OFF_HIST + 65536)      // 64
#define OFF_SBASE (OFF_CUT + 64)          // 16*1024*4 = 65,536
#define OFF_GBCUR (OFF_SBASE + 65536)     // 16*1024*64 = 1,048,576 (padded ctrs)
#define OFF_KEYS  (OFF_GBCUR + 1048576)   // 16*8192*8 = 1,048,576
#define OFF_ECNT  (OFF_KEYS + 1048576)    // 2048
#define OFF_EDGE  (OFF_ECNT + 2048)       // 16*65536*4 = 4,194,304
#define OFF_GRP   (OFF_EDGE + 4194304)    // 4,194,304
// bucket arrays overlaid on GRP (dead before k_nms3 might write grouped):
#define OFF_BOFS  (OFF_GRP)               // 16*130*4 (pad to 16384)
#define OFF_SIDX  (OFF_GRP + 16384)       // u32 [16*5120]
#define OFF_SBX1  (OFF_SIDX + 327680)
#define OFF_SBX2  (OFF_SBX1 + 327680)
#define OFF_SBY1  (OFF_SBX2 + 327680)
#define OFF_SBY2  (OFF_SBY1 + 327680)
#define OFF_SBAR  (OFF_SBY2 + 327680)

__device__ __forceinline__ unsigned f2ord(float f) {
    unsigned u = __float_as_uint(f);
    return (u & 0x80000000u) ? ~u : (u | 0x80000000u);
}
__device__ __forceinline__ float ord2f(unsigned o) {
    unsigned u = (o & 0x80000000u) ? (o ^ 0x80000000u) : ~o;
    return __uint_as_float(u);
}
// monotone x1 -> bucket map; identical in k_bucket and k_pair3
__device__ __forceinline__ int bucketOf(float x) {
    int b = (int)((x + 0.6f) * 71.111115f);   // 128 buckets over [-0.6, 1.2]
    return (b < 0) ? 0 : ((b > 127) ? 127 : b);
}

// K1: per-image histogram over the 1024-bucket window in LDS + atomic merge.
__global__ void __launch_bounds__(256) k_hist(const float* __restrict__ conf,
                                              unsigned* __restrict__ hist) {
    __shared__ unsigned lh[NB2];
    int img = blockIdx.y;
    for (int i = threadIdx.x; i < NB2; i += 256) lh[i] = 0;
    __syncthreads();
    const float4* src = (const float4*)(conf + (size_t)img * PNUM * 2);
    int stride = gridDim.x * 256;
    for (int q = blockIdx.x * 256 + threadIdx.x; q < HPNUM; q += stride) {
        float4 v = src[q];
        if (v.y > 0.01f) atomicAdd(&lh[(f2ord(v.y) >> 16) - B2BASE], 1u);
        if (v.w > 0.01f) atomicAdd(&lh[(f2ord(v.w) >> 16) - B2BASE], 1u);
    }
    __syncthreads();
    unsigned* h = hist + (size_t)img * NB2;
    for (int i = threadIdx.x; i < NB2; i += 256) {
        unsigned c = lh[i];
        if (c) atomicAdd(&h[i], c);
    }
}

// K2: cutoff + per-bucket suffix base ranks (segment start slots).
__global__ void __launch_bounds__(256) k_cutoff2(const unsigned* __restrict__ hist,
                                                 unsigned* __restrict__ cut,
                                                 unsigned* __restrict__ sbase) {
    __shared__ unsigned csum[256], suf[256];
    int img = blockIdx.x;
    int t = threadIdx.x;
    const unsigned* h = hist + (size_t)img * NB2;
    unsigned h0 = h[t * 4], h1 = h[t * 4 + 1], h2 = h[t * 4 + 2], h3 = h[t * 4 + 3];
    csum[t] = h0 + h1 + h2 + h3;
    __syncthreads();
    if (t == 0) {
        unsigned a = 0;
        for (int g = 255; g >= 0; --g) { unsigned c = csum[g]; suf[g] = a; a += c; }
        unsigned acc = 0, before = 0;
        int c = -1;
        for (int cc = 255; cc >= 0; --cc) {
            if (acc + csum[cc] >= (unsigned)TOPK) { c = cc; before = acc; break; }
            acc += csum[cc];
        }
        unsigned cutb = B2BASE;
        if (c >= 0) {
            unsigned s2 = before;
            cutb = B2BASE + (unsigned)c * 4u;
            for (int b = c * 4 + 3; b >= c * 4; --b) {
                s2 += h[b];
                if (s2 >= (unsigned)TOPK) { cutb = B2BASE + (unsigned)b; break; }
            }
        }
        cut[img] = cutb;
    }
    __syncthreads();
    unsigned a = suf[t];
    unsigned* sb = sbase + (size_t)img * NB2 + t * 4;
    sb[3] = a;
    sb[2] = a + h3;
    sb[1] = a + h3 + h2;
    sb[0] = a + h3 + h2 + h1;
}

// K3: gather candidates directly into their bucket segment (rank-scatter).
__global__ void __launch_bounds__(256) k_gather2(
        const float* __restrict__ conf, const unsigned* __restrict__ cut,
        const unsigned* __restrict__ sbase, unsigned* __restrict__ gbcur,
        unsigned long long* __restrict__ keys) {
    int q = blockIdx.x * 256 + threadIdx.x;
    int img = blockIdx.y;
    if (q >= HPNUM) return;
    unsigned cutb = cut[img];
    float4 v = ((const float4*)(conf + (size_t)img * PNUM * 2))[q];
    const unsigned* sb = sbase + (size_t)img * NB2;
    unsigned* gc = gbcur + (size_t)img * NB2 * 16;
    unsigned long long* kp = keys + (size_t)img * CAP;
    #pragma unroll
    for (int e = 0; e < 2; ++e) {
        float s = e ? v.w : v.y;
        if (s > 0.01f) {
            unsigned o = f2ord(s);
            if ((o >> 16) >= cutb) {
                unsigned wb = (o >> 16) - B2BASE;
                unsigned pos = sb[wb] + atomicAdd(&gc[wb * 16], 1u);
                if (pos < (unsigned)CAP)
                    kp[pos] = ((unsigned long long)o << 32)
                              | (unsigned)(~(unsigned)(2 * q + e));
            }
        }
    }
}

// K4: per-segment descending sort (<=1024 keys). One block per (bucket,img).
__global__ void __launch_bounds__(256) k_ssort(
        unsigned long long* __restrict__ keys, const unsigned* __restrict__ hist,
        const unsigned* __restrict__ cut, const unsigned* __restrict__ sbase) {
    int img = blockIdx.y;
    int b = blockIdx.x;
    if (B2BASE + (unsigned)b < cut[img]) return;
    unsigned cnt = hist[(size_t)img * NB2 + b];
    if (cnt <= 1) return;
    if (cnt > 1024) cnt = 1024;
    unsigned base = sbase[(size_t)img * NB2 + b];
    __shared__ unsigned long long sk[1024];
    unsigned long long* kp = keys + (size_t)img * CAP + base;
    int tid = threadIdx.x;
    for (int i = tid; i < 1024; i += 256) sk[i] = (i < (int)cnt) ? kp[i] : 0ull;
    __syncthreads();
    for (int k = 2; k <= 1024; k <<= 1) {
        for (int j = k >> 1; j > 0; j >>= 1) {
            for (int t = tid; t < 512; t += 256) {
                int i = ((t & ~(j - 1)) << 1) | (t & (j - 1));
                int p = i | j;
                bool desc = ((i & k) == 0);
                unsigned long long a = sk[i], bb = sk[p];
                bool sw = desc ? (a < bb) : (a > bb);
                if (sw) { sk[i] = bb; sk[p] = a; }
            }
            __syncthreads();
        }
    }
    for (int i = tid; i < (int)cnt; i += 256) kp[i] = sk[i];
}

// K5: decode sorted top-5000 keys -> SC/X1/Y1/X2/Y2/AREA
__global__ void __launch_bounds__(256) k_decode(
        const unsigned long long* __restrict__ keys,
        const float* __restrict__ loc, const float* __restrict__ pri,
        float* __restrict__ SC, float* __restrict__ X1, float* __restrict__ Y1,
        float* __restrict__ X2, float* __restrict__ Y2, float* __restrict__ AREA) {
    int gidx = blockIdx.x * 256 + threadIdx.x;
    if (gidx >= BNUM * TOPK) return;
    int img = gidx / TOPK;
    int r = gidx - img * TOPK;
    unsigned long long key = keys[(size_t)img * CAP + r];
    size_t o = (size_t)img * TOPK + r;
    if (key != 0ull) {
        unsigned ordv = (unsigned)(key >> 32);
        float s = ord2f(ordv);
        unsigned p = ~(unsigned)(key & 0xFFFFFFFFull);
        const float* lp = loc + ((size_t)img * PNUM + p) * 4;
        const float* pp = pri + (size_t)p * 4;
        float lx = lp[0], ly = lp[1], lw = lp[2], lh = lp[3];
        float px = pp[0], py = pp[1], pw = pp[2], ph = pp[3];
        float cx = px + (lx * 0.1f) * pw;
        float cy = py + (ly * 0.1f) * ph;
        float w = pw * expf(lw * 0.2f);
        float h = ph * expf(lh * 0.2f);
        float x1 = cx - w * 0.5f;
        float y1 = cy - h * 0.5f;
        float x2 = x1 + w;
        float y2 = y1 + h;
        SC[o] = s; X1[o] = x1; Y1[o] = y1; X2[o] = x2; Y2[o] = y2;
        AREA[o] = (x2 - x1) * (y2 - y1);
    } else {
        SC[o] = -1.0f; X1[o] = 0.f; Y1[o] = 0.f; X2[o] = 0.f; Y2[o] = 0.f;
        AREA[o] = 0.f;
    }
}

// K6: spatial bucketing by x1 (counting sort into 128 buckets). 1 block/image.
__global__ void __launch_bounds__(256) k_bucket(
        const float* __restrict__ X1, const float* __restrict__ X2,
        const float* __restrict__ Y1, const float* __restrict__ Y2,
        const float* __restrict__ AREA,
        unsigned* __restrict__ bofs, unsigned* __restrict__ sidx,
        float* __restrict__ sbx1, float* __restrict__ sbx2,
        float* __restrict__ sby1, float* __restrict__ sby2,
        float* __restrict__ sbar) {
    __shared__ unsigned bcnt[NXB], bpre[NXB + 1], bcur[NXB];
    int img = blockIdx.x;
    int tid = threadIdx.x;
    if (tid < NXB) bcnt[tid] = 0;
    __syncthreads();
    size_t ib = (size_t)img * TOPK;
    for (int r = tid; r < TOPK; r += 256)
        atomicAdd(&bcnt[bucketOf(X1[ib + r])], 1u);
    __syncthreads();
    if (tid == 0) {
        unsigned a = 0;
        for (int b = 0; b < NXB; ++b) { bpre[b] = a; a += bcnt[b]; }
        bpre[NXB] = a;
    }
    __syncthreads();
    if (tid < NXB) bcur[tid] = bpre[tid];
    if (tid <= NXB) bofs[img * 130 + tid] = bpre[tid];
    __syncthreads();
    int base = img * BSTRIDE;
    for (int r = tid; r < TOPK; r += 256) {
        float x = X1[ib + r];
        unsigned s = atomicAdd(&bcur[bucketOf(x)], 1u);
        sidx[base + s] = (unsigned)r;
        sbx1[base + s] = x;
        sbx2[base + s] = X2[ib + r];
        sby1[base + s] = Y1[ib + r];
        sby2[base + s] = Y2[ib + r];
        sbar[base + s] = AREA[ib + r];
    }
}

// K7: wave-per-sorted-slot bucketed pair search (see R17).
__global__ void __launch_bounds__(256) k_pair3(
        const unsigned* __restrict__ bofs, const unsigned* __restrict__ sidx,
        const float* __restrict__ sbx1, const float* __restrict__ sbx2,
        const float* __restrict__ sby1, const float* __restrict__ sby2,
        const float* __restrict__ sbar,
        unsigned* __restrict__ ecnt, unsigned* __restrict__ edges) {
    __shared__ unsigned ebuf[EBUF];
    __shared__ unsigned ecl, ebase;
    int img = blockIdx.y;
    int wid = threadIdx.x >> 6;
    int lane = threadIdx.x & 63;
    int s = blockIdx.x * 4 + wid;
    if (threadIdx.x == 0) ecl = 0;
    __syncthreads();
    unsigned* ec = ecnt + (size_t)img * GSTRIDE;
    unsigned* eg = edges + (size_t)img * CAPE;
    if (s < TOPK) {
        int base = img * BSTRIDE;
        float x1 = sbx1[base + s], x2 = sbx2[base + s];
        float y1 = sby1[base + s], y2 = sby2[base + s];
        float ar = sbar[base + s];
        unsigned r = sidx[base + s];
        int b1 = bucketOf(x1), b2 = bucketOf(x2);
        const unsigned* bo = bofs + img * 130;
        unsigned s0 = bo[b1], s1 = bo[b2 + 1];
        for (unsigned sb = s0 + lane; ; sb += 64) {
            bool hit = false;
            unsigned edge = 0;
            if (sb < s1) {
                float bx1 = sbx1[base + sb];
                if (bx1 >= x1) {
                    unsigned r2 = sidx[base + sb];
                    if (!(bx1 == x1 && r2 <= r)) {
                        float bx2 = sbx2[base + sb];
                        float dx = fminf(x2, bx2) - fmaxf(x1, bx1);
                        if (dx > 0.0f) {
                            float by1 = sby1[base + sb];
                            float by2 = sby2[base + sb];
                            float dy = fminf(y2, by2) - fmaxf(y1, by1);
                            if (dy > 0.0f) {
                                float inter = dx * dy;
                                float iou = inter /
                                    (sbar[base + sb] + ar - inter);
                                if (iou > 0.3f) {
                                    unsigned su = (r < r2) ? r : r2;
                                    unsigned vi = (r < r2) ? r2 : r;
                                    edge = (vi << 13) | su;
                                    hit = true;
                                }
                            }
                        }
                    }
                }
            }
            unsigned long long bal = __ballot(hit);
            if (bal) {
                int n = __popcll(bal);
                unsigned wb = 0;
                if (lane == 0) wb = atomicAdd(&ecl, (unsigned)n);
                wb = __shfl(wb, 0, 64);
                if (hit) {
                    unsigned long long lt =
                        (lane == 0) ? 0ull : ((1ull << lane) - 1ull);
                    unsigned p = wb + (unsigned)__popcll(bal & lt);
                    if (p < (unsigned)EBUF) ebuf[p] = edge;
                    else {
                        unsigned gp = atomicAdd(ec, 1u);
                        if (gp < (unsigned)CAPE) eg[gp] = edge;
                    }
                }
            }
            if (sb - lane + 64 >= s1) break;
        }
    }
    __syncthreads();
    unsigned n = min(ecl, (unsigned)EBUF);
    if (threadIdx.x == 0 && n) ebase = atomicAdd(ec, n);
    __syncthreads();
    for (unsigned i = threadIdx.x; i < n; i += 256) {
        unsigned p = ebase + i;
        if (p < (unsigned)CAPE) eg[p] = ebuf[i];
    }
}

// K8: sparse greedy resolve + compaction, fully LDS-resident serial loop.
//  - validity ballots precomputed in parallel (all 4 waves) -> validw[]
//  - grouped edges counting-sorted into LDS (<= ELDS; global fallback)
//  - wave-0 79-tile serial resolve touches ONLY LDS
__global__ void __launch_bounds__(256) k_nms3(
        const float* __restrict__ SC, const float* __restrict__ X1,
        const float* __restrict__ Y1, const float* __restrict__ X2,
        const float* __restrict__ Y2,
        const unsigned* __restrict__ ecnt, const unsigned* __restrict__ edges,
        unsigned* __restrict__ grouped, float* __restrict__ out) {
    __shared__ unsigned lgrp[ELDS];               // 40 KiB grouped edges
    __shared__ unsigned cnt[80], ofs[80], cur[80];
    __shared__ unsigned long long keepw[80];
    __shared__ unsigned long long validw[80];
    __shared__ unsigned pfx[80];
    __shared__ unsigned inLo[64], inHi[64];
    __shared__ unsigned remS[2];
    int img = blockIdx.x;
    int tid = threadIdx.x;
    int l = tid & 63;
    int wid = tid >> 6;
    size_t ib = (size_t)img * TOPK;
    const float* sc = SC + ib;

    if (tid < 80) cnt[tid] = 0;
    // validity preload: waves handle disjoint tiles in parallel
    for (int w = wid; w < NWORDS; w += 4) {
        int row = w * 64 + l;
        bool valid = (row < TOPK) && (sc[row] > 0.01f);
        unsigned long long b = __ballot(valid);
        if (l == 0) validw[w] = b;
    }
    __syncthreads();

    unsigned E = min(ecnt[(size_t)img * GSTRIDE], (unsigned)CAPE);
    const unsigned* eimg = edges + (size_t)img * CAPE;
    unsigned* gimg = grouped + (size_t)img * CAPE;
    bool inl = (E <= (unsigned)ELDS);             // uniform across block
    for (unsigned e = tid; e < E; e += 256) atomicAdd(&cnt[eimg[e] >> 19], 1u);
    __syncthreads();
    if (tid == 0) {
        unsigned a = 0;
        for (int w = 0; w < NWORDS; ++w) { ofs[w] = a; a += cnt[w]; }
    }
    __syncthreads();
    if (tid < 80) cur[tid] = ofs[tid];
    __syncthreads();
    for (unsigned e = tid; e < E; e += 256) {
        unsigned ed = eimg[e];
        unsigned p = atomicAdd(&cur[ed >> 19], 1u);
        if (inl) lgrp[p] = ed; else gimg[p] = ed;
    }
    __syncthreads();

    // wave-0 serial-over-tiles resolve (LDS-only on the critical path)
    if (wid == 0) {
        for (int t = 0; t < NWORDS; ++t) {
            inLo[l] = 0; inHi[l] = 0;
            if (l < 2) remS[l] = 0;
            unsigned c = cnt[t], o = ofs[t];
            for (unsigned k = l; k < c; k += 64) {
                unsigned ed = inl ? lgrp[o + k] : gimg[o + k];
                unsigned v = ed >> 13, s = ed & 8191u;
                unsigned vb = v & 63u, sb = s & 63u;
                int st = (int)(s >> 6);
                if (st == t) {
                    if (sb < 32) atomicOr(&inLo[vb], 1u << sb);
                    else         atomicOr(&inHi[vb], 1u << (sb - 32));
                } else {
                    unsigned long long kw = keepw[st];   // finalized (st < t)
                    if ((kw >> sb) & 1ull) {
                        if (vb < 32) atomicOr(&remS[0], 1u << vb);
                        else         atomicOr(&remS[1], 1u << (vb - 32));
                    }
                }
            }
            __builtin_amdgcn_s_waitcnt(0);   // drain LDS ops before reads
            unsigned long long inW =
                ((unsigned long long)inHi[l] << 32) | inLo[l];
            unsigned long long remW =
                ((unsigned long long)remS[1] << 32) | remS[0];
            bool alive = ((validw[t] >> l) & 1ull) && !((remW >> l) & 1ull);
            while (true) {                   // exact ascending greedy
                unsigned long long aliveW = __ballot(alive);
                unsigned long long pend =
                    __ballot(alive && ((inW & aliveW) != 0ull));
                if (!pend) break;
                int v = __builtin_ctzll(pend);
                if (l == v) alive = false;
            }
            unsigned long long kwv = __ballot(alive);
            if (l == 0) keepw[t] = kwv;
        }
    }
    __syncthreads();

    // prefix + compacted output write
    if (tid == 0) {
        unsigned acc = 0;
        for (int w = 0; w < NWORDS; ++w) { pfx[w] = acc; acc += (unsigned)__popcll(keepw[w]); }
    }
    __syncthreads();
    const float* x1 = X1 + ib; const float* y1 = Y1 + ib;
    const float* x2 = X2 + ib; const float* y2 = Y2 + ib;
    float* op = out + (((size_t)img * 2) + 1) * TOPK * 5;
    for (int w = wid; w < NWORDS; w += 4) {
        unsigned long long kw = keepw[w];
        if (!kw) continue;
        int row = w * 64 + l;
        if ((kw >> l) & 1ull) {
            int rank = (int)pfx[w] + (int)__popcll(kw & ((1ull << l) - 1ull));
            float* r = op + (size_t)rank * 5;
            r[0] = sc[row]; r[1] = x1[row]; r[2] = y1[row];
            r[3] = x2[row]; r[4] = y2[row];
        }
    }
}

extern "C" void kernel_launch(void* const* d_in, const int* in_sizes, int n_in,
                              void* d_out, int out_size, void* d_ws, size_t ws_size,
                              hipStream_t stream) {
    (void)in_sizes; (void)n_in; (void)ws_size;
    const float* loc  = (const float*)d_in[0];   // (16, 136500, 4)
    const float* conf = (const float*)d_in[1];   // (16*136500, 2)
    const float* pri  = (const float*)d_in[2];   // (136500, 4)
    float* out = (float*)d_out;                  // (16, 2, 5000, 5)
    char* ws = (char*)d_ws;

    float* SC   = (float*)(ws + OFF_SC);
    float* X1   = (float*)(ws + OFF_X1);
    float* Y1   = (float*)(ws + OFF_Y1);
    float* X2   = (float*)(ws + OFF_X2);
    float* Y2   = (float*)(ws + OFF_Y2);
    float* AREA = (float*)(ws + OFF_AREA);
    unsigned* hist = (unsigned*)(ws + OFF_HIST);
    unsigned* cut  = (unsigned*)(ws + OFF_CUT);
    unsigned* sbase = (unsigned*)(ws + OFF_SBASE);
    unsigned* gbcur = (unsigned*)(ws + OFF_GBCUR);
    unsigned long long* keys = (unsigned long long*)(ws + OFF_KEYS);
    unsigned* ecnt = (unsigned*)(ws + OFF_ECNT);
    unsigned* edges = (unsigned*)(ws + OFF_EDGE);
    unsigned* grouped = (unsigned*)(ws + OFF_GRP);
    unsigned* bofs = (unsigned*)(ws + OFF_BOFS);
    unsigned* sidx = (unsigned*)(ws + OFF_SIDX);
    float* sbx1 = (float*)(ws + OFF_SBX1);
    float* sbx2 = (float*)(ws + OFF_SBX2);
    float* sby1 = (float*)(ws + OFF_SBY1);
    float* sby2 = (float*)(ws + OFF_SBY2);
    float* sbar = (float*)(ws + OFF_SBAR);

    hipMemsetAsync(d_out, 0, (size_t)out_size * sizeof(float), stream);
    // zero hist..ecnt contiguously (covers cut/sbase/gbcur/keys/ecnt)
    hipMemsetAsync(ws + OFF_HIST, 0, (OFF_ECNT + 2048) - OFF_HIST, stream);

    dim3 gh1(16, BNUM);                          // 16 grid-stride blocks/image
    k_hist<<<gh1, 256, 0, stream>>>(conf, hist);
    k_cutoff2<<<BNUM, 256, 0, stream>>>(hist, cut, sbase);
    dim3 gh2((HPNUM + 255) / 256, BNUM);
    k_gather2<<<gh2, 256, 0, stream>>>(conf, cut, sbase, gbcur, keys);
    dim3 gs(NB2, BNUM);                          // per-segment sorts
    k_ssort<<<gs, 256, 0, stream>>>(keys, hist, cut, sbase);
    k_decode<<<(BNUM * TOPK + 255) / 256, 256, 0, stream>>>(
        keys, loc, pri, SC, X1, Y1, X2, Y2, AREA);

    // sparse NMS: spatial bucketing + slot-mapped pair search + LDS resolve
    k_bucket<<<BNUM, 256, 0, stream>>>(X1, X2, Y1, Y2, AREA,
                                       bofs, sidx, sbx1, sbx2, sby1, sby2, sbar);
    dim3 pg((TOPK + 3) / 4, BNUM);               // one wave per sorted slot
    k_pair3<<<pg, 256, 0, stream>>>(bofs, sidx, sbx1, sbx2, sby1, sby2, sbar,
                                    ecnt, edges);
    k_nms3<<<BNUM, 256, 0, stream>>>(SC, X1, Y1, X2, Y2, ecnt, edges, grouped, out);
}

// Round 19
// 286.753 us; speedup vs baseline: 1.2020x; 1.1347x over previous
//
#include <hip/hip_runtime.h>
#include <math.h>

#pragma clang fp contract(off)

// Problem constants (match reference)
#define PNUM 136500      // sum of f*f
#define HPNUM 68250      // PNUM/2 (exact)
#define BNUM 16
#define TOPK 5000
#define CAP 8192         // candidate capacity per image
#define NB2 1024         // histogram window buckets (covers ord16 of (0.01, 1.0))
#define B2BASE 0xBC00u   // window base: f2ord(0.01)>>16 = 0xBC23 >= 0xBC00
#define NWORDS 79        // ceil(5000/64)
#define GSTRIDE 32       // ecnt padding: 32 u32 = 128 B per image
#define CAPE 65536       // edge capacity per image (expected E ~ 1-3k)
#define ELDS 10240       // LDS grouped-edge capacity (global fallback beyond)
#define NXB 128          // spatial x1 buckets
#define BSTRIDE 5120     // per-image bucket-array stride (>= TOPK)
#define EBUF 3072        // per-block LDS edge buffer

// Workspace layout (bytes).
#define OFF_SC    ((size_t)0)
#define OFF_X1    (OFF_SC + 320000)
#define OFF_Y1    (OFF_X1 + 320000)
#define OFF_X2    (OFF_Y1 + 320000)
#define OFF_Y2    (OFF_X2 + 320000)
#define OFF_AREA  (OFF_Y2 + 320000)       // ends 1,920,000
#define OFF_HIST  ((size_t)1920000)       // 16*1024*4 = 65,536
#define OFF_CUT   (OFF_HIST + 65536)      // 64
#define OFF_SBASE (OFF_CUT + 64)          // 16*1024*4 = 65,536
#define OFF_GBCUR (OFF_SBASE + 65536)     // 16*1024*64 = 1,048,576 (padded ctrs)
#define OFF_KEYS  (OFF_GBCUR + 1048576)   // 16*8192*8 = 1,048,576
#define OFF_ECNT  (OFF_KEYS + 1048576)    // 2048
#define OFF_EDGE  (OFF_ECNT + 2048)       // 16*65536*4 = 4,194,304
#define OFF_GRP   (OFF_EDGE + 4194304)    // 4,194,304
// bucket arrays overlaid on GRP (dead before k_nms3 might write grouped):
#define OFF_BOFS  (OFF_GRP)               // 16*130*4 (pad to 16384)
#define OFF_SIDX  (OFF_GRP + 16384)       // u32 [16*5120]
#define OFF_SBX1  (OFF_SIDX + 327680)
#define OFF_SBX2  (OFF_SBX1 + 327680)
#define OFF_SBY1  (OFF_SBX2 + 327680)
#define OFF_SBY2  (OFF_SBY1 + 327680)
#define OFF_SBAR  (OFF_SBY2 + 327680)

__device__ __forceinline__ unsigned f2ord(float f) {
    unsigned u = __float_as_uint(f);
    return (u & 0x80000000u) ? ~u : (u | 0x80000000u);
}
__device__ __forceinline__ float ord2f(unsigned o) {
    unsigned u = (o & 0x80000000u) ? (o ^ 0x80000000u) : ~o;
    return __uint_as_float(u);
}
// monotone x1 -> bucket map; identical in k_bucket and k_pair4
__device__ __forceinline__ int bucketOf(float x) {
    int b = (int)((x + 0.6f) * 71.111115f);   // 128 buckets over [-0.6, 1.2]
    return (b < 0) ? 0 : ((b > 127) ? 127 : b);
}

// K1: per-image histogram over the 1024-bucket window in LDS + atomic merge.
__global__ void __launch_bounds__(256) k_hist(const float* __restrict__ conf,
                                              unsigned* __restrict__ hist) {
    __shared__ unsigned lh[NB2];
    int img = blockIdx.y;
    for (int i = threadIdx.x; i < NB2; i += 256) lh[i] = 0;
    __syncthreads();
    const float4* src = (const float4*)(conf + (size_t)img * PNUM * 2);
    int stride = gridDim.x * 256;
    for (int q = blockIdx.x * 256 + threadIdx.x; q < HPNUM; q += stride) {
        float4 v = src[q];
        if (v.y > 0.01f) atomicAdd(&lh[(f2ord(v.y) >> 16) - B2BASE], 1u);
        if (v.w > 0.01f) atomicAdd(&lh[(f2ord(v.w) >> 16) - B2BASE], 1u);
    }
    __syncthreads();
    unsigned* h = hist + (size_t)img * NB2;
    for (int i = threadIdx.x; i < NB2; i += 256) {
        unsigned c = lh[i];
        if (c) atomicAdd(&h[i], c);
    }
}

// K2: cutoff + per-bucket suffix base ranks (segment start slots).
__global__ void __launch_bounds__(256) k_cutoff2(const unsigned* __restrict__ hist,
                                                 unsigned* __restrict__ cut,
                                                 unsigned* __restrict__ sbase) {
    __shared__ unsigned csum[256], suf[256];
    int img = blockIdx.x;
    int t = threadIdx.x;
    const unsigned* h = hist + (size_t)img * NB2;
    unsigned h0 = h[t * 4], h1 = h[t * 4 + 1], h2 = h[t * 4 + 2], h3 = h[t * 4 + 3];
    csum[t] = h0 + h1 + h2 + h3;
    __syncthreads();
    if (t == 0) {
        unsigned a = 0;
        for (int g = 255; g >= 0; --g) { unsigned c = csum[g]; suf[g] = a; a += c; }
        unsigned acc = 0, before = 0;
        int c = -1;
        for (int cc = 255; cc >= 0; --cc) {
            if (acc + csum[cc] >= (unsigned)TOPK) { c = cc; before = acc; break; }
            acc += csum[cc];
        }
        unsigned cutb = B2BASE;
        if (c >= 0) {
            unsigned s2 = before;
            cutb = B2BASE + (unsigned)c * 4u;
            for (int b = c * 4 + 3; b >= c * 4; --b) {
                s2 += h[b];
                if (s2 >= (unsigned)TOPK) { cutb = B2BASE + (unsigned)b; break; }
            }
        }
        cut[img] = cutb;
    }
    __syncthreads();
    unsigned a = suf[t];
    unsigned* sb = sbase + (size_t)img * NB2 + t * 4;
    sb[3] = a;
    sb[2] = a + h3;
    sb[1] = a + h3 + h2;
    sb[0] = a + h3 + h2 + h1;
}

// K3: gather candidates directly into their bucket segment (rank-scatter).
__global__ void __launch_bounds__(256) k_gather2(
        const float* __restrict__ conf, const unsigned* __restrict__ cut,
        const unsigned* __restrict__ sbase, unsigned* __restrict__ gbcur,
        unsigned long long* __restrict__ keys) {
    int q = blockIdx.x * 256 + threadIdx.x;
    int img = blockIdx.y;
    if (q >= HPNUM) return;
    unsigned cutb = cut[img];
    float4 v = ((const float4*)(conf + (size_t)img * PNUM * 2))[q];
    const unsigned* sb = sbase + (size_t)img * NB2;
    unsigned* gc = gbcur + (size_t)img * NB2 * 16;
    unsigned long long* kp = keys + (size_t)img * CAP;
    #pragma unroll
    for (int e = 0; e < 2; ++e) {
        float s = e ? v.w : v.y;
        if (s > 0.01f) {
            unsigned o = f2ord(s);
            if ((o >> 16) >= cutb) {
                unsigned wb = (o >> 16) - B2BASE;
                unsigned pos = sb[wb] + atomicAdd(&gc[wb * 16], 1u);
                if (pos < (unsigned)CAP)
                    kp[pos] = ((unsigned long long)o << 32)
                              | (unsigned)(~(unsigned)(2 * q + e));
            }
        }
    }
}

// K4: per-segment descending sort (<=1024 keys). One block per (bucket,img).
__global__ void __launch_bounds__(256) k_ssort(
        unsigned long long* __restrict__ keys, const unsigned* __restrict__ hist,
        const unsigned* __restrict__ cut, const unsigned* __restrict__ sbase) {
    int img = blockIdx.y;
    int b = blockIdx.x;
    if (B2BASE + (unsigned)b < cut[img]) return;
    unsigned cnt = hist[(size_t)img * NB2 + b];
    if (cnt <= 1) return;
    if (cnt > 1024) cnt = 1024;
    unsigned base = sbase[(size_t)img * NB2 + b];
    __shared__ unsigned long long sk[1024];
    unsigned long long* kp = keys + (size_t)img * CAP + base;
    int tid = threadIdx.x;
    for (int i = tid; i < 1024; i += 256) sk[i] = (i < (int)cnt) ? kp[i] : 0ull;
    __syncthreads();
    for (int k = 2; k <= 1024; k <<= 1) {
        for (int j = k >> 1; j > 0; j >>= 1) {
            for (int t = tid; t < 512; t += 256) {
                int i = ((t & ~(j - 1)) << 1) | (t & (j - 1));
                int p = i | j;
                bool desc = ((i & k) == 0);
                unsigned long long a = sk[i], bb = sk[p];
                bool sw = desc ? (a < bb) : (a > bb);
                if (sw) { sk[i] = bb; sk[p] = a; }
            }
            __syncthreads();
        }
    }
    for (int i = tid; i < (int)cnt; i += 256) kp[i] = sk[i];
}

// K5: decode sorted top-5000 keys -> SC/X1/Y1/X2/Y2/AREA
__global__ void __launch_bounds__(256) k_decode(
        const unsigned long long* __restrict__ keys,
        const float* __restrict__ loc, const float* __restrict__ pri,
        float* __restrict__ SC, float* __restrict__ X1, float* __restrict__ Y1,
        float* __restrict__ X2, float* __restrict__ Y2, float* __restrict__ AREA) {
    int gidx = blockIdx.x * 256 + threadIdx.x;
    if (gidx >= BNUM * TOPK) return;
    int img = gidx / TOPK;
    int r = gidx - img * TOPK;
    unsigned long long key = keys[(size_t)img * CAP + r];
    size_t o = (size_t)img * TOPK + r;
    if (key != 0ull) {
        unsigned ordv = (unsigned)(key >> 32);
        float s = ord2f(ordv);
        unsigned p = ~(unsigned)(key & 0xFFFFFFFFull);
        const float* lp = loc + ((size_t)img * PNUM + p) * 4;
        const float* pp = pri + (size_t)p * 4;
        float lx = lp[0], ly = lp[1], lw = lp[2], lh = lp[3];
        float px = pp[0], py = pp[1], pw = pp[2], ph = pp[3];
        float cx = px + (lx * 0.1f) * pw;
        float cy = py + (ly * 0.1f) * ph;
        float w = pw * expf(lw * 0.2f);
        float h = ph * expf(lh * 0.2f);
        float x1 = cx - w * 0.5f;
        float y1 = cy - h * 0.5f;
        float x2 = x1 + w;
        float y2 = y1 + h;
        SC[o] = s; X1[o] = x1; Y1[o] = y1; X2[o] = x2; Y2[o] = y2;
        AREA[o] = (x2 - x1) * (y2 - y1);
    } else {
        SC[o] = -1.0f; X1[o] = 0.f; Y1[o] = 0.f; X2[o] = 0.f; Y2[o] = 0.f;
        AREA[o] = 0.f;
    }
}

// K6: spatial bucketing by x1 (counting sort into 128 buckets). 1 block/image.
__global__ void __launch_bounds__(256) k_bucket(
        const float* __restrict__ X1, const float* __restrict__ X2,
        const float* __restrict__ Y1, const float* __restrict__ Y2,
        const float* __restrict__ AREA,
        unsigned* __restrict__ bofs, unsigned* __restrict__ sidx,
        float* __restrict__ sbx1, float* __restrict__ sbx2,
        float* __restrict__ sby1, float* __restrict__ sby2,
        float* __restrict__ sbar) {
    __shared__ unsigned bcnt[NXB], bpre[NXB + 1], bcur[NXB];
    int img = blockIdx.x;
    int tid = threadIdx.x;
    if (tid < NXB) bcnt[tid] = 0;
    __syncthreads();
    size_t ib = (size_t)img * TOPK;
    for (int r = tid; r < TOPK; r += 256)
        atomicAdd(&bcnt[bucketOf(X1[ib + r])], 1u);
    __syncthreads();
    if (tid == 0) {
        unsigned a = 0;
        for (int b = 0; b < NXB; ++b) { bpre[b] = a; a += bcnt[b]; }
        bpre[NXB] = a;
    }
    __syncthreads();
    if (tid < NXB) bcur[tid] = bpre[tid];
    if (tid <= NXB) bofs[img * 130 + tid] = bpre[tid];
    __syncthreads();
    int base = img * BSTRIDE;
    for (int r = tid; r < TOPK; r += 256) {
        float x = X1[ib + r];
        unsigned s = atomicAdd(&bcur[bucketOf(x)], 1u);
        sidx[base + s] = (unsigned)r;
        sbx1[base + s] = x;
        sbx2[base + s] = X2[ib + r];
        sby1[base + s] = Y1[ib + r];
        sby2[base + s] = Y2[ib + r];
        sbar[base + s] = AREA[ib + r];
    }
}

// K7: 4-slot-per-wave bucketed pair search. A wave owns 4 CONSECUTIVE sorted
// slots (bucket index monotone in slot -> union range covers each box's own
// range); the union candidate range is streamed ONCE and tested against 4
// register-resident boxes. Predicates (bx1>=x1, tie on index, dx/dy>0)
// reject out-of-range pairs -> bit-identical edge set to per-box scan.
// Preamble loads are wave-uniform (scalar). Ballot-compacted LDS emission.
__global__ void __launch_bounds__(256) k_pair4(
        const unsigned* __restrict__ bofs, const unsigned* __restrict__ sidx,
        const float* __restrict__ sbx1, const float* __restrict__ sbx2,
        const float* __restrict__ sby1, const float* __restrict__ sby2,
        const float* __restrict__ sbar,
        unsigned* __restrict__ ecnt, unsigned* __restrict__ edges) {
    __shared__ unsigned ebuf[EBUF];
    __shared__ unsigned ecl, ebase;
    int img = blockIdx.y;
    int wid = threadIdx.x >> 6;
    int lane = threadIdx.x & 63;
    int sb0 = (blockIdx.x * 4 + wid) * 4;         // first of 4 slots
    if (threadIdx.x == 0) ecl = 0;
    __syncthreads();
    unsigned* ec = ecnt + (size_t)img * GSTRIDE;
    unsigned* eg = edges + (size_t)img * CAPE;
    if (sb0 < TOPK) {
        int base = img * BSTRIDE;
        float x1k[4], x2k[4], y1k[4], y2k[4], ark[4];
        unsigned rk[4];
        bool act[4];
        #pragma unroll
        for (int k = 0; k < 4; ++k) {
            act[k] = (sb0 + k) < TOPK;
            int s = act[k] ? (sb0 + k) : sb0;
            x1k[k] = sbx1[base + s]; x2k[k] = sbx2[base + s];
            y1k[k] = sby1[base + s]; y2k[k] = sby2[base + s];
            ark[k] = sbar[base + s]; rk[k] = sidx[base + s];
        }
        int b1 = bucketOf(x1k[0]);                // min bucket (slot-monotone)
        int b2m = bucketOf(x2k[0]);
        #pragma unroll
        for (int k = 1; k < 4; ++k)
            if (act[k]) { int b = bucketOf(x2k[k]); if (b > b2m) b2m = b; }
        const unsigned* bo = bofs + img * 130;
        unsigned s0 = bo[b1], s1 = bo[b2m + 1];
        for (unsigned sb = s0 + lane; ; sb += 64) {
            bool in = (sb < s1);
            float bx1 = 0.f, bx2 = 0.f, by1 = 0.f, by2 = 0.f, bar = 0.f;
            unsigned r2 = 0;
            if (in) {
                bx1 = sbx1[base + sb]; bx2 = sbx2[base + sb];
                by1 = sby1[base + sb]; by2 = sby2[base + sb];
                bar = sbar[base + sb]; r2 = sidx[base + sb];
            }
            #pragma unroll
            for (int k = 0; k < 4; ++k) {
                bool hit = false;
                unsigned edge = 0;
                if (in && act[k] && bx1 >= x1k[k]
                    && !(bx1 == x1k[k] && r2 <= rk[k])) {
                    float dx = fminf(x2k[k], bx2) - fmaxf(x1k[k], bx1);
                    if (dx > 0.0f) {
                        float dy = fminf(y2k[k], by2) - fmaxf(y1k[k], by1);
                        if (dy > 0.0f) {
                            float inter = dx * dy;
                            float iou = inter / (bar + ark[k] - inter);
                            if (iou > 0.3f) {
                                unsigned su = (rk[k] < r2) ? rk[k] : r2;
                                unsigned vi = (rk[k] < r2) ? r2 : rk[k];
                                edge = (vi << 13) | su;
                                hit = true;
                            }
                        }
                    }
                }
                unsigned long long bal = __ballot(hit);
                if (bal) {
                    int n = __popcll(bal);
                    unsigned wb = 0;
                    if (lane == 0) wb = atomicAdd(&ecl, (unsigned)n);
                    wb = __shfl(wb, 0, 64);
                    if (hit) {
                        unsigned long long lt =
                            (lane == 0) ? 0ull : ((1ull << lane) - 1ull);
                        unsigned p = wb + (unsigned)__popcll(bal & lt);
                        if (p < (unsigned)EBUF) ebuf[p] = edge;
                        else {
                            unsigned gp = atomicAdd(ec, 1u);
                            if (gp < (unsigned)CAPE) eg[gp] = edge;
                        }
                    }
                }
            }
            if (sb - lane + 64 >= s1) break;      // uniform across wave
        }
    }
    __syncthreads();
    unsigned n = min(ecl, (unsigned)EBUF);
    if (threadIdx.x == 0 && n) ebase = atomicAdd(ec, n);
    __syncthreads();
    for (unsigned i = threadIdx.x; i < n; i += 256) {
        unsigned p = ebase + i;
        if (p < (unsigned)CAPE) eg[p] = ebuf[i];
    }
}

// K8: sparse greedy resolve + compaction, fully LDS-resident serial loop.
__global__ void __launch_bounds__(256) k_nms3(
        const float* __restrict__ SC, const float* __restrict__ X1,
        const float* __restrict__ Y1, const float* __restrict__ X2,
        const float* __restrict__ Y2,
        const unsigned* __restrict__ ecnt, const unsigned* __restrict__ edges,
        unsigned* __restrict__ grouped, float* __restrict__ out) {
    __shared__ unsigned lgrp[ELDS];               // 40 KiB grouped edges
    __shared__ unsigned cnt[80], ofs[80], cur[80];
    __shared__ unsigned long long keepw[80];
    __shared__ unsigned long long validw[80];
    __shared__ unsigned pfx[80];
    __shared__ unsigned inLo[64], inHi[64];
    __shared__ unsigned remS[2];
    int img = blockIdx.x;
    int tid = threadIdx.x;
    int l = tid & 63;
    int wid = tid >> 6;
    size_t ib = (size_t)img * TOPK;
    const float* sc = SC + ib;

    if (tid < 80) cnt[tid] = 0;
    for (int w = wid; w < NWORDS; w += 4) {
        int row = w * 64 + l;
        bool valid = (row < TOPK) && (sc[row] > 0.01f);
        unsigned long long b = __ballot(valid);
        if (l == 0) validw[w] = b;
    }
    __syncthreads();

    unsigned E = min(ecnt[(size_t)img * GSTRIDE], (unsigned)CAPE);
    const unsigned* eimg = edges + (size_t)img * CAPE;
    unsigned* gimg = grouped + (size_t)img * CAPE;
    bool inl = (E <= (unsigned)ELDS);             // uniform across block
    for (unsigned e = tid; e < E; e += 256) atomicAdd(&cnt[eimg[e] >> 19], 1u);
    __syncthreads();
    if (tid == 0) {
        unsigned a = 0;
        for (int w = 0; w < NWORDS; ++w) { ofs[w] = a; a += cnt[w]; }
    }
    __syncthreads();
    if (tid < 80) cur[tid] = ofs[tid];
    __syncthreads();
    for (unsigned e = tid; e < E; e += 256) {
        unsigned ed = eimg[e];
        unsigned p = atomicAdd(&cur[ed >> 19], 1u);
        if (inl) lgrp[p] = ed; else gimg[p] = ed;
    }
    __syncthreads();

    if (wid == 0) {
        for (int t = 0; t < NWORDS; ++t) {
            inLo[l] = 0; inHi[l] = 0;
            if (l < 2) remS[l] = 0;
            unsigned c = cnt[t], o = ofs[t];
            for (unsigned k = l; k < c; k += 64) {
                unsigned ed = inl ? lgrp[o + k] : gimg[o + k];
                unsigned v = ed >> 13, s = ed & 8191u;
                unsigned vb = v & 63u, sb = s & 63u;
                int st = (int)(s >> 6);
                if (st == t) {
                    if (sb < 32) atomicOr(&inLo[vb], 1u << sb);
                    else         atomicOr(&inHi[vb], 1u << (sb - 32));
                } else {
                    unsigned long long kw = keepw[st];   // finalized (st < t)
                    if ((kw >> sb) & 1ull) {
                        if (vb < 32) atomicOr(&remS[0], 1u << vb);
                        else         atomicOr(&remS[1], 1u << (vb - 32));
                    }
                }
            }
            __builtin_amdgcn_s_waitcnt(0);   // drain LDS ops before reads
            unsigned long long inW =
                ((unsigned long long)inHi[l] << 32) | inLo[l];
            unsigned long long remW =
                ((unsigned long long)remS[1] << 32) | remS[0];
            bool alive = ((validw[t] >> l) & 1ull) && !((remW >> l) & 1ull);
            while (true) {                   // exact ascending greedy
                unsigned long long aliveW = __ballot(alive);
                unsigned long long pend =
                    __ballot(alive && ((inW & aliveW) != 0ull));
                if (!pend) break;
                int v = __builtin_ctzll(pend);
                if (l == v) alive = false;
            }
            unsigned long long kwv = __ballot(alive);
            if (l == 0) keepw[t] = kwv;
        }
    }
    __syncthreads();

    if (tid == 0) {
        unsigned acc = 0;
        for (int w = 0; w < NWORDS; ++w) { pfx[w] = acc; acc += (unsigned)__popcll(keepw[w]); }
    }
    __syncthreads();
    const float* x1 = X1 + ib; const float* y1 = Y1 + ib;
    const float* x2 = X2 + ib; const float* y2 = Y2 + ib;
    float* op = out + (((size_t)img * 2) + 1) * TOPK * 5;
    for (int w = wid; w < NWORDS; w += 4) {
        unsigned long long kw = keepw[w];
        if (!kw) continue;
        int row = w * 64 + l;
        if ((kw >> l) & 1ull) {
            int rank = (int)pfx[w] + (int)__popcll(kw & ((1ull << l) - 1ull));
            float* r = op + (size_t)rank * 5;
            r[0] = sc[row]; r[1] = x1[row]; r[2] = y1[row];
            r[3] = x2[row]; r[4] = y2[row];
        }
    }
}

extern "C" void kernel_launch(void* const* d_in, const int* in_sizes, int n_in,
                              void* d_out, int out_size, void* d_ws, size_t ws_size,
                              hipStream_t stream) {
    (void)in_sizes; (void)n_in; (void)ws_size;
    const float* loc  = (const float*)d_in[0];   // (16, 136500, 4)
    const float* conf = (const float*)d_in[1];   // (16*136500, 2)
    const float* pri  = (const float*)d_in[2];   // (136500, 4)
    float* out = (float*)d_out;                  // (16, 2, 5000, 5)
    char* ws = (char*)d_ws;

    float* SC   = (float*)(ws + OFF_SC);
    float* X1   = (float*)(ws + OFF_X1);
    float* Y1   = (float*)(ws + OFF_Y1);
    float* X2   = (float*)(ws + OFF_X2);
    float* Y2   = (float*)(ws + OFF_Y2);
    float* AREA = (float*)(ws + OFF_AREA);
    unsigned* hist = (unsigned*)(ws + OFF_HIST);
    unsigned* cut  = (unsigned*)(ws + OFF_CUT);
    unsigned* sbase = (unsigned*)(ws + OFF_SBASE);
    unsigned* gbcur = (unsigned*)(ws + OFF_GBCUR);
    unsigned long long* keys = (unsigned long long*)(ws + OFF_KEYS);
    unsigned* ecnt = (unsigned*)(ws + OFF_ECNT);
    unsigned* edges = (unsigned*)(ws + OFF_EDGE);
    unsigned* grouped = (unsigned*)(ws + OFF_GRP);
    unsigned* bofs = (unsigned*)(ws + OFF_BOFS);
    unsigned* sidx = (unsigned*)(ws + OFF_SIDX);
    float* sbx1 = (float*)(ws + OFF_SBX1);
    float* sbx2 = (float*)(ws + OFF_SBX2);
    float* sby1 = (float*)(ws + OFF_SBY1);
    float* sby2 = (float*)(ws + OFF_SBY2);
    float* sbar = (float*)(ws + OFF_SBAR);

    hipMemsetAsync(d_out, 0, (size_t)out_size * sizeof(float), stream);
    hipMemsetAsync(ws + OFF_HIST, 0, (OFF_ECNT + 2048) - OFF_HIST, stream);

    dim3 gh1(16, BNUM);                          // 16 grid-stride blocks/image
    k_hist<<<gh1, 256, 0, stream>>>(conf, hist);
    k_cutoff2<<<BNUM, 256, 0, stream>>>(hist, cut, sbase);
    dim3 gh2((HPNUM + 255) / 256, BNUM);
    k_gather2<<<gh2, 256, 0, stream>>>(conf, cut, sbase, gbcur, keys);
    dim3 gs(NB2, BNUM);                          // per-segment sorts
    k_ssort<<<gs, 256, 0, stream>>>(keys, hist, cut, sbase);
    k_decode<<<(BNUM * TOPK + 255) / 256, 256, 0, stream>>>(
        keys, loc, pri, SC, X1, Y1, X2, Y2, AREA);

    // sparse NMS: spatial bucketing + 4-slot wave pair search + LDS resolve
    k_bucket<<<BNUM, 256, 0, stream>>>(X1, X2, Y1, Y2, AREA,
                                       bofs, sidx, sbx1, sbx2, sby1, sby2, sbar);
    dim3 pg((TOPK + 15) / 16, BNUM);             // 4 waves x 4 slots per block
    k_pair4<<<pg, 256, 0, stream>>>(bofs, sidx, sbx1, sbx2, sby1, sby2, sbar,
                                    ecnt, edges);
    k_nms3<<<BNUM, 256, 0, stream>>>(SC, X1, Y1, X2, Y2, ecnt, edges, grouped, out);
}